// Round 3
// baseline (3969.466 us; speedup 1.0000x reference)
//
#include <hip/hip_runtime.h>
#include <math.h>

#define BB   16
#define TFULL 4096
#define T2   2048
#define LSEQ 2019
#define HSTR 2048
#define CIN  64
#define CO   32
#define HD   64
#define NST  64
#define NLAY 8
#define DOUT 640
#define EPSF 1e-5f
#define NCH  32
#define CHL  64

static __device__ __forceinline__ float sigm(float x){ return 1.f/(1.f + __expf(-x)); }
static __device__ __forceinline__ float gelu_(float x){ return 0.5f*x*(1.f + erff(x*0.7071067811865475f)); }

// ---------------- Stage A: pw1 conv + GN1 partial stats ----------------
__global__ void __launch_bounds__(256) k_pw1(const float* __restrict__ x,
                                             const float* __restrict__ w,
                                             const float* __restrict__ bias,
                                             float* __restrict__ u1,
                                             float* __restrict__ stats){
  int blk = blockIdx.x;
  int b  = blk >> 6;
  int t0 = (blk & 63) << 6;
  __shared__ float xs[CIN][64];
  __shared__ float wsm[CO*CIN];
  __shared__ float red[8];
  int tid = threadIdx.x;
  for (int i = tid; i < CIN*64; i += 256){
    int c = i >> 6, t = i & 63;
    xs[c][t] = x[((long)(b*CIN + c))*TFULL + t0 + t];
  }
  for (int i = tid; i < CO*CIN; i += 256) wsm[i] = w[i];
  __syncthreads();
  int t  = tid & 63;
  int o0 = tid >> 6;
  float lsum = 0.f, lsq = 0.f;
  for (int o = o0; o < CO; o += 4){
    float acc = bias[o];
    #pragma unroll
    for (int c = 0; c < CIN; ++c) acc = fmaf(wsm[o*CIN + c], xs[c][t], acc);
    u1[((long)(b*CO + o))*TFULL + t0 + t] = acc;
    lsum += acc; lsq += acc*acc;
  }
  #pragma unroll
  for (int off = 32; off; off >>= 1){ lsum += __shfl_down(lsum, off); lsq += __shfl_down(lsq, off); }
  if ((tid & 63) == 0){ red[tid>>6] = lsum; red[4 + (tid>>6)] = lsq; }
  __syncthreads();
  if (tid == 0){
    atomicAdd(&stats[b],      red[0]+red[1]+red[2]+red[3]);
    atomicAdd(&stats[16 + b], red[4]+red[5]+red[6]+red[7]);
  }
}

__global__ void k_gnstat(float* __restrict__ stats, int which, float cnt){
  int b = threadIdx.x;
  if (b < BB){
    int o = which * 64;
    float m = stats[o + b] / cnt;
    float v = stats[o + 16 + b] / cnt - m*m;
    stats[o + 32 + b] = m;
    stats[o + 48 + b] = rsqrtf(v + EPSF);
  }
}

// ---------------- Stage A3: GN1 apply + GLU(time) + SiLU ----------------
__global__ void __launch_bounds__(256) k_glu_silu(const float* __restrict__ u1,
                                                  const float* __restrict__ g,
                                                  const float* __restrict__ bb,
                                                  const float* __restrict__ stats,
                                                  float* __restrict__ u2){
  int blk = blockIdx.x;
  int b  = blk >> 5;
  int t0 = (blk & 31) << 6;
  float m = stats[32 + b], r = stats[48 + b];
  int tid = threadIdx.x;
  int t = t0 + (tid & 63);
  for (int c = tid >> 6; c < CO; c += 4){
    long base = ((long)(b*CO + c))*TFULL;
    float a  = u1[base + t];
    float bv = u1[base + t + T2];
    float gc = g[c], bc = bb[c];
    a  = (a  - m)*r*gc + bc;
    bv = (bv - m)*r*gc + bc;
    float z = a * sigm(bv);
    z = z * sigm(z);
    u2[((long)(b*CO + c))*T2 + t] = z;
  }
}

// ---------------- Stage B1: depthwise conv (K=32, pad 1) + GN2 partial stats ----------------
__global__ void __launch_bounds__(256) k_dconv(const float* __restrict__ u2,
                                               const float* __restrict__ w,
                                               const float* __restrict__ bias,
                                               float* __restrict__ v,
                                               float* __restrict__ stats){
  int blk = blockIdx.x;
  int b = blk >> 5, c = blk & 31;
  __shared__ float row[T2 + 2];
  __shared__ float red[8];
  int tid = threadIdx.x;
  if (tid == 0){ row[0] = 0.f; row[T2 + 1] = 0.f; }
  const float* src = u2 + ((long)(b*CO + c))*T2;
  for (int i = tid; i < T2; i += 256) row[1 + i] = src[i];
  __syncthreads();
  float wk[32];
  #pragma unroll
  for (int k = 0; k < 32; ++k) wk[k] = w[c*32 + k];
  float bc = bias[c];
  float lsum = 0.f, lsq = 0.f;
  float* dst = v + ((long)(b*CO + c))*LSEQ;
  for (int t = tid; t < LSEQ; t += 256){
    float acc = bc;
    #pragma unroll
    for (int k = 0; k < 32; ++k) acc = fmaf(wk[k], row[t + k], acc);
    dst[t] = acc;
    lsum += acc; lsq += acc*acc;
  }
  #pragma unroll
  for (int off = 32; off; off >>= 1){ lsum += __shfl_down(lsum, off); lsq += __shfl_down(lsq, off); }
  if ((tid & 63) == 0){ red[tid>>6] = lsum; red[4 + (tid>>6)] = lsq; }
  __syncthreads();
  if (tid == 0){
    atomicAdd(&stats[64 + b], red[0]+red[1]+red[2]+red[3]);
    atomicAdd(&stats[80 + b], red[4]+red[5]+red[6]+red[7]);
  }
}

// ---------------- Stage B3: GN2 apply + pw2 + encoder -> h (B,HD,HSTR) ----------------
__global__ void __launch_bounds__(256) k_pw2enc(const float* __restrict__ v,
                                                const float* __restrict__ g2,
                                                const float* __restrict__ b2,
                                                const float* __restrict__ pw2w,
                                                const float* __restrict__ pw2b,
                                                const float* __restrict__ encw,
                                                const float* __restrict__ encb,
                                                const float* __restrict__ stats,
                                                float* __restrict__ h){
  int blk = blockIdx.x;
  int b  = blk >> 5;
  int t0 = (blk & 31) << 6;
  int tcnt = min(64, LSEQ - t0);
  __shared__ float vn[CO][64];
  __shared__ float p2[CO*CO];
  __shared__ float ew[CO*HD];
  __shared__ float u3[4][CO];
  __shared__ float hout[HD][65];
  int tid = threadIdx.x;
  float m = stats[96 + b], r = stats[112 + b];
  for (int i = tid; i < CO*CO; i += 256){
    int o = i & 31, c = i >> 5;
    p2[c*CO + o] = pw2w[o*CO + c];
  }
  for (int i = tid; i < CO*HD; i += 256) ew[i] = encw[i];
  for (int i = tid; i < CO*64; i += 256){
    int c = i >> 6, t = i & 63;
    float val = 0.f;
    if (t < tcnt) val = v[((long)(b*CO + c))*LSEQ + t0 + t];
    vn[c][t] = (val - m)*r*g2[c] + b2[c];
  }
  __syncthreads();
  int wv = tid >> 6, ln = tid & 63;
  for (int i = 0; i < 16; ++i){
    int tt = wv*16 + i;
    if (ln < CO){
      float acc = pw2b[ln];
      #pragma unroll
      for (int c = 0; c < CO; ++c) acc = fmaf(p2[c*CO + ln], vn[c][tt], acc);
      u3[wv][ln] = acc;
    }
    float hacc = encb[ln];
    #pragma unroll
    for (int c = 0; c < CO; ++c) hacc = fmaf(ew[c*HD + ln], u3[wv][c], hacc);
    hout[ln][tt] = hacc;
  }
  __syncthreads();
  for (int i = tid; i < HD*64; i += 256){
    int d = i >> 6, t = i & 63;
    if (t < tcnt) h[((long)(b*HD + d))*HSTR + t0 + t] = hout[d][t];
  }
}

// ---------------- S4D coefficients for ALL layers ----------------
__global__ void k_coef(const float* __restrict__ log_dt, const float* __restrict__ logA,
                       const float* __restrict__ Aim, const float* __restrict__ Cre,
                       const float* __restrict__ Cim, float* __restrict__ coef){
  int blk = blockIdx.x;
  int l = blk >> 6, hh = blk & 63;
  int n = threadIdx.x;
  float dt = expf(log_dt[l*HD + hh]);
  int idx = (l*HD + hh)*NST + n;
  float Ar = -expf(logA[idx]);
  float Ai = Aim[idx];
  float dr = Ar*dt, di = Ai*dt;
  float er = expf(dr);
  float wr = er*cosf(di), wi = er*sinf(di);
  float inv = 1.f/(Ar*Ar + Ai*Ai);
  float xr = wr - 1.f, xi = wi;
  float qr = (xr*Ar + xi*Ai)*inv;
  float qi = (xi*Ar - xr*Ai)*inv;
  float cr = Cre[idx], ci = Cim[idx];
  float cdr = cr*qr - ci*qi;
  float cdi = cr*qi + ci*qr;
  float* cl = coef + l*4*HD*NST;
  int hn = hh*NST + n;
  cl[hn]            = wr;
  cl[HD*NST + hn]   = wi;
  cl[2*HD*NST + hn] = cdr;
  cl[3*HD*NST + hn] = cdi;
}

// ---------------- S4D chunk-parallel scan ----------------
// E2p[np][k] = float4 (2cd_{2np} w^k .re/.im, 2cd_{2np+1} w^k .re/.im), k=0..64
__global__ void __launch_bounds__(256) k_s4d(const float* __restrict__ h,
                                             const float* __restrict__ coef,
                                             int layer, float* __restrict__ y){
  int blk = blockIdx.x;
  int b = blk >> 6, hh = blk & 63;
  __shared__ float u_s[2048];
  __shared__ float E2p[32*65*4];
  __shared__ float S_s[NCH*128];
  __shared__ float Kpad[128];
  int tid = threadIdx.x;
  int n = tid & 63, q = tid >> 6;
  const float* cl = coef + layer*4*HD*NST;
  int hn = hh*NST + n;
  float wr  = cl[hn];
  float wi  = cl[HD*NST + hn];
  float cdr = cl[2*HD*NST + hn];
  float cdi = cl[3*HD*NST + hn];
  const float* up = h + ((long)(b*HD + hh))*HSTR;

  {
    int base = tid*8;
    if (base + 8 <= LSEQ){
      *(float4*)&u_s[base]     = *(const float4*)(up + base);
      *(float4*)&u_s[base + 4] = *(const float4*)(up + base + 4);
    } else {
      #pragma unroll
      for (int k = 0; k < 8; ++k){
        int t = base + k;
        u_s[t] = (t < LSEQ) ? up[t] : 0.f;
      }
    }
  }
  if (tid < 64) Kpad[tid] = 0.f;

  // build E2p rows: thread (n,q) fills k in [16q,16q+16) (q==3: +17 incl k=64)
  {
    float ar = wr, ai = wi;
    #pragma unroll
    for (int s = 0; s < 4; ++s){ float t2 = ar*ar - ai*ai; ai = 2.f*ar*ai; ar = t2; }
    float pr = 1.f, pi = 0.f;
    for (int k = 0; k < q; ++k){ float t2 = pr*ar - pi*ai; pi = pr*ai + pi*ar; pr = t2; }
    int np = n >> 1, par = n & 1;
    float* bp = &E2p[(np*65 + q*16)*4 + par*2];
    int cnt = (q == 3) ? 17 : 16;
    for (int k = 0; k < cnt; ++k){
      float2 ev;
      ev.x = 2.f*(cdr*pr - cdi*pi);
      ev.y = 2.f*(cdr*pi + cdi*pr);
      *(float2*)bp = ev;
      float t2 = pr*wr - pi*wi; pi = pr*wi + pi*wr; pr = t2;
      bp += 4;
    }
  }
  __syncthreads();

  // phase 1: per-chunk decayed input sums (wave q owns chunks q*8..q*8+7)
  int cbase = q*8;
  {
    float vr[8], vi[8];
    #pragma unroll
    for (int c8 = 0; c8 < 8; ++c8){ vr[c8] = 0.f; vi[c8] = 0.f; }
    for (int j4 = 0; j4 < 64; j4 += 4){
      float4 uu[8];
      #pragma unroll
      for (int c8 = 0; c8 < 8; ++c8) uu[c8] = *(const float4*)&u_s[(cbase + c8)*64 + j4];
      #pragma unroll
      for (int jj = 0; jj < 4; ++jj){
        #pragma unroll
        for (int c8 = 0; c8 < 8; ++c8){
          float uj = (jj==0)?uu[c8].x:(jj==1)?uu[c8].y:(jj==2)?uu[c8].z:uu[c8].w;
          float nr = fmaf(wr, vr[c8], fmaf(-wi, vi[c8], uj));
          float ni = fmaf(wr, vi[c8], wi*vr[c8]);
          vr[c8] = nr; vi[c8] = ni;
        }
      }
    }
    #pragma unroll
    for (int c8 = 0; c8 < 8; ++c8){
      S_s[(cbase + c8)*128 + 2*n]     = vr[c8];
      S_s[(cbase + c8)*128 + 2*n + 1] = vi[c8];
    }
  }
  __syncthreads();

  // phase 2 (wave 0): K taps + chunk-state scan
  if (q == 0){
    float ks = 0.f;
    for (int np = 0; np < 32; ++np){
      float4 e = *(const float4*)&E2p[(np*65 + n)*4];
      ks += e.x + e.z;
    }
    Kpad[64 + n] = ks;
    float ar = wr, ai = wi;
    #pragma unroll
    for (int s = 0; s < 6; ++s){ float t2 = ar*ar - ai*ai; ai = 2.f*ar*ai; ar = t2; }
    float sr = 0.f, si = 0.f;
    for (int c = 0; c < NCH; ++c){
      float vr2 = S_s[c*128 + 2*n], vi2 = S_s[c*128 + 2*n + 1];
      S_s[c*128 + 2*n]     = sr;
      S_s[c*128 + 2*n + 1] = si;
      float nr = fmaf(ar, sr, fmaf(-ai, si, vr2));
      float ni = fmaf(ar, si, fmaf(ai, sr, vi2));
      sr = nr; si = ni;
    }
  }
  __syncthreads();

  // phase 3: 2 groups of 4 chunks, lane = i
  float* yo = y + ((long)(b*HD + hh))*HSTR;
  int i = n;
  #pragma unroll
  for (int g = 0; g < 2; ++g){
    int c0 = cbase + g*4;
    float acc0 = 0.f, acc1 = 0.f, acc2 = 0.f, acc3 = 0.f;
    for (int np = 0; np < 32; ++np){
      float4 e  = *(const float4*)&E2p[(np*65 + i + 1)*4];
      float4 s0 = *(const float4*)&S_s[(c0+0)*128 + np*4];
      float4 s1 = *(const float4*)&S_s[(c0+1)*128 + np*4];
      float4 s2 = *(const float4*)&S_s[(c0+2)*128 + np*4];
      float4 s3 = *(const float4*)&S_s[(c0+3)*128 + np*4];
      acc0 = fmaf(e.x,s0.x, fmaf(-e.y,s0.y, fmaf(e.z,s0.z, fmaf(-e.w,s0.w, acc0))));
      acc1 = fmaf(e.x,s1.x, fmaf(-e.y,s1.y, fmaf(e.z,s1.z, fmaf(-e.w,s1.w, acc1))));
      acc2 = fmaf(e.x,s2.x, fmaf(-e.y,s2.y, fmaf(e.z,s2.z, fmaf(-e.w,s2.w, acc2))));
      acc3 = fmaf(e.x,s3.x, fmaf(-e.y,s3.y, fmaf(e.z,s3.z, fmaf(-e.w,s3.w, acc3))));
    }
    for (int j4 = 0; j4 < 64; j4 += 4){
      float4 u0 = *(const float4*)&u_s[(c0+0)*64 + j4];
      float4 u1v= *(const float4*)&u_s[(c0+1)*64 + j4];
      float4 u2v= *(const float4*)&u_s[(c0+2)*64 + j4];
      float4 u3v= *(const float4*)&u_s[(c0+3)*64 + j4];
      #pragma unroll
      for (int jj = 0; jj < 4; ++jj){
        float kv = Kpad[64 + i - j4 - jj];
        float a0 = (jj==0)?u0.x:(jj==1)?u0.y:(jj==2)?u0.z:u0.w;
        float a1 = (jj==0)?u1v.x:(jj==1)?u1v.y:(jj==2)?u1v.z:u1v.w;
        float a2 = (jj==0)?u2v.x:(jj==1)?u2v.y:(jj==2)?u2v.z:u2v.w;
        float a3 = (jj==0)?u3v.x:(jj==1)?u3v.y:(jj==2)?u3v.z:u3v.w;
        acc0 = fmaf(kv, a0, acc0);
        acc1 = fmaf(kv, a1, acc1);
        acc2 = fmaf(kv, a2, acc2);
        acc3 = fmaf(kv, a3, acc3);
      }
    }
    int t0c = c0*64 + i;
    if (t0c        < LSEQ) yo[t0c]        = acc0;
    if (t0c + 64   < LSEQ) yo[t0c + 64]   = acc1;
    if (t0c + 128  < LSEQ) yo[t0c + 128]  = acc2;
    if (t0c + 192  < LSEQ) yo[t0c + 192]  = acc3;
  }
}

// ---------------- S4D post: register-tiled GEMM + GLU + residual + LN ----------------
__global__ void __launch_bounds__(256) k_post(const float* __restrict__ y,
                                              float* __restrict__ h,
                                              const float* __restrict__ D,
                                              const float* __restrict__ ow,
                                              const float* __restrict__ ob,
                                              const float* __restrict__ lng,
                                              const float* __restrict__ lnb,
                                              int layer){
  int blk = blockIdx.x;
  int b  = blk >> 5;
  int t0 = (blk & 31) << 6;
  __shared__ float Ws[64*128];     // [c][o]
  __shared__ float Ys[64*68];      // [c][t]; reused as z-buffer
  __shared__ float mstat[64], rstat[64];
  int tid = threadIdx.x;
  const float* owp = ow + layer*2*HD*HD;
  const float* obp = ob + layer*2*HD;
  // stage W^T
  {
    int o = tid >> 1, cs = (tid & 1)*32;
    const float* wrow = owp + o*HD + cs;
    #pragma unroll
    for (int k = 0; k < 8; ++k){
      float4 w4 = *(const float4*)(wrow + k*4);
      Ws[(cs + k*4 + 0)*128 + o] = w4.x;
      Ws[(cs + k*4 + 1)*128 + o] = w4.y;
      Ws[(cs + k*4 + 2)*128 + o] = w4.z;
      Ws[(cs + k*4 + 3)*128 + o] = w4.w;
    }
  }
  // stage Y = gelu(y + D*h)
  {
    int c = tid >> 2, qq = tid & 3;
    float dl = D[layer*HD + c];
    const float* yrow = y + ((long)(b*HD + c))*HSTR + t0 + qq*16;
    const float* hrow = h + ((long)(b*HD + c))*HSTR + t0 + qq*16;
    #pragma unroll
    for (int k = 0; k < 4; ++k){
      float4 yv = *(const float4*)(yrow + k*4);
      float4 hv = *(const float4*)(hrow + k*4);
      float4 g4;
      g4.x = gelu_(fmaf(hv.x, dl, yv.x));
      g4.y = gelu_(fmaf(hv.y, dl, yv.y));
      g4.z = gelu_(fmaf(hv.z, dl, yv.z));
      g4.w = gelu_(fmaf(hv.w, dl, yv.w));
      *(float4*)&Ys[c*68 + qq*16 + k*4] = g4;
    }
  }
  __syncthreads();
  int og = tid >> 4, tg = tid & 15;
  int o0 = og*4, tt0 = tg*4;
  float accA[4][4], accG[4][4];
  #pragma unroll
  for (int i = 0; i < 4; ++i){
    float ba = obp[o0 + i], bg = obp[64 + o0 + i];
    #pragma unroll
    for (int j = 0; j < 4; ++j){ accA[i][j] = ba; accG[i][j] = bg; }
  }
  for (int c = 0; c < 64; ++c){
    float4 wa = *(const float4*)&Ws[c*128 + o0];
    float4 wg = *(const float4*)&Ws[c*128 + 64 + o0];
    float4 yv = *(const float4*)&Ys[c*68 + tt0];
    float yvv[4] = {yv.x, yv.y, yv.z, yv.w};
    float wav[4] = {wa.x, wa.y, wa.z, wa.w};
    float wgv[4] = {wg.x, wg.y, wg.z, wg.w};
    #pragma unroll
    for (int i = 0; i < 4; ++i){
      #pragma unroll
      for (int j = 0; j < 4; ++j){
        accA[i][j] = fmaf(wav[i], yvv[j], accA[i][j]);
        accG[i][j] = fmaf(wgv[i], yvv[j], accG[i][j]);
      }
    }
  }
  __syncthreads();
  // GLU + residual -> zs (reuse Ys)
  float r[4][4];
  #pragma unroll
  for (int i = 0; i < 4; ++i){
    int c = o0 + i;
    const float* hrow = h + ((long)(b*HD + c))*HSTR + t0 + tt0;
    #pragma unroll
    for (int j = 0; j < 4; ++j){
      int t = t0 + tt0 + j;
      float hold = (t < LSEQ) ? hrow[j] : 0.f;
      float z = accA[i][j] * sigm(accG[i][j]);
      r[i][j] = z + hold;
    }
    float4 rr = {r[i][0], r[i][1], r[i][2], r[i][3]};
    *(float4*)&Ys[c*68 + tt0] = rr;
  }
  __syncthreads();
  // LN column stats
  if (tid < 64){
    float s1 = 0.f, s2 = 0.f;
    for (int c = 0; c < 64; ++c){
      float v = Ys[c*68 + tid];
      s1 += v; s2 += v*v;
    }
    float m = s1 * (1.f/64.f);
    float var = fmaf(-m, m, s2 * (1.f/64.f));
    mstat[tid] = m;
    rstat[tid] = rsqrtf(var + EPSF);
  }
  __syncthreads();
  #pragma unroll
  for (int i = 0; i < 4; ++i){
    int c = o0 + i;
    float gl = lng[layer*HD + c], bl = lnb[layer*HD + c];
    float* hrow = h + ((long)(b*HD + c))*HSTR + t0 + tt0;
    if (t0 + tt0 + 3 < LSEQ){
      float4 o4v;
      o4v.x = fmaf((r[i][0] - mstat[tt0+0])*rstat[tt0+0], gl, bl);
      o4v.y = fmaf((r[i][1] - mstat[tt0+1])*rstat[tt0+1], gl, bl);
      o4v.z = fmaf((r[i][2] - mstat[tt0+2])*rstat[tt0+2], gl, bl);
      o4v.w = fmaf((r[i][3] - mstat[tt0+3])*rstat[tt0+3], gl, bl);
      *(float4*)hrow = o4v;
    } else {
      #pragma unroll
      for (int j = 0; j < 4; ++j){
        int t = t0 + tt0 + j;
        if (t < LSEQ) hrow[j] = fmaf((r[i][j] - mstat[tt0+j])*rstat[tt0+j], gl, bl);
      }
    }
  }
}

// ---------------- Decoder: register-blocked, weight-reuse GEMM ----------------
__global__ void __launch_bounds__(320) k_dec(const float* __restrict__ h,
                                             const float* __restrict__ w,
                                             const float* __restrict__ bias,
                                             float* __restrict__ out){
  int blk = blockIdx.x;
  int b  = blk >> 6;
  int t0 = (blk & 63) << 5;
  __shared__ float hl[HD][32];
  int tid = threadIdx.x;
  for (int i = tid; i < HD*32; i += 320){
    int d = i >> 5, t = i & 31;
    int tt = t0 + t;
    hl[d][t] = (tt < LSEQ) ? h[((long)(b*HD + d))*HSTR + tt] : 0.f;
  }
  __syncthreads();
  int o4 = tid % 160, th = tid / 160;
  int tb = th * 16;
  float4 acc[16];
  const float4 b4 = *(const float4*)(bias + o4*4);
  #pragma unroll
  for (int i = 0; i < 16; ++i) acc[i] = b4;
  const float* wp = w + o4*4;
  for (int d = 0; d < HD; ++d){
    float4 w4 = *(const float4*)(wp + (long)d*DOUT);
    #pragma unroll
    for (int ii = 0; ii < 4; ++ii){
      float4 h4 = *(const float4*)&hl[d][tb + ii*4];
      float hvv[4] = {h4.x, h4.y, h4.z, h4.w};
      #pragma unroll
      for (int jj = 0; jj < 4; ++jj){
        int i = ii*4 + jj;
        acc[i].x = fmaf(hvv[jj], w4.x, acc[i].x);
        acc[i].y = fmaf(hvv[jj], w4.y, acc[i].y);
        acc[i].z = fmaf(hvv[jj], w4.z, acc[i].z);
        acc[i].w = fmaf(hvv[jj], w4.w, acc[i].w);
      }
    }
  }
  #pragma unroll
  for (int i = 0; i < 16; ++i){
    int t = t0 + tb + i;
    if (t < LSEQ) *(float4*)(out + ((long)(b*LSEQ) + t)*DOUT + o4*4) = acc[i];
  }
}

extern "C" void kernel_launch(void* const* d_in, const int* in_sizes, int n_in,
                              void* d_out, int out_size, void* d_ws, size_t ws_size,
                              hipStream_t stream){
  const float* x     = (const float*)d_in[0];
  const float* pw1_w = (const float*)d_in[1];
  const float* pw1_b = (const float*)d_in[2];
  const float* gn1_g = (const float*)d_in[3];
  const float* gn1_b = (const float*)d_in[4];
  const float* dw_w  = (const float*)d_in[5];
  const float* dw_b  = (const float*)d_in[6];
  const float* gn2_g = (const float*)d_in[7];
  const float* gn2_b = (const float*)d_in[8];
  const float* pw2_w = (const float*)d_in[9];
  const float* pw2_b = (const float*)d_in[10];
  const float* enc_w = (const float*)d_in[11];
  const float* enc_b = (const float*)d_in[12];
  const float* log_dt= (const float*)d_in[13];
  const float* logA  = (const float*)d_in[14];
  const float* Aim   = (const float*)d_in[15];
  const float* Cre   = (const float*)d_in[16];
  const float* Cim   = (const float*)d_in[17];
  const float* Dp    = (const float*)d_in[18];
  const float* owp   = (const float*)d_in[19];
  const float* obp   = (const float*)d_in[20];
  const float* lng   = (const float*)d_in[21];
  const float* lnb   = (const float*)d_in[22];
  const float* dec_w = (const float*)d_in[23];
  const float* dec_b = (const float*)d_in[24];
  float* out = (float*)d_out;

  float* ws   = (float*)d_ws;
  float* u1   = ws;
  float* u2   = u1 + 2097152;
  float* vv   = u2 + 1048576;
  float* hbuf = vv + 1033728;
  float* coef = hbuf + 2097152;
  float* stats= coef + 131072;
  float* ybuf = u1;

  hipMemsetAsync(stats, 0, 128*sizeof(float), stream);
  k_coef<<<NLAY*HD, 64, 0, stream>>>(log_dt, logA, Aim, Cre, Cim, coef);
  k_pw1<<<BB*64, 256, 0, stream>>>(x, pw1_w, pw1_b, u1, stats);
  k_gnstat<<<1, 64, 0, stream>>>(stats, 0, (float)(CO*TFULL));
  k_glu_silu<<<BB*32, 256, 0, stream>>>(u1, gn1_g, gn1_b, stats, u2);
  k_dconv<<<BB*CO, 256, 0, stream>>>(u2, dw_w, dw_b, vv, stats);
  k_gnstat<<<1, 64, 0, stream>>>(stats, 1, (float)(CO*LSEQ));
  k_pw2enc<<<BB*32, 256, 0, stream>>>(vv, gn2_g, gn2_b, pw2_w, pw2_b, enc_w, enc_b, stats, hbuf);
  for (int l = 0; l < NLAY; ++l){
    k_s4d<<<BB*HD, 256, 0, stream>>>(hbuf, coef, l, ybuf);
    k_post<<<BB*32, 256, 0, stream>>>(ybuf, hbuf, Dp, owp, obp, lng, lnb, l);
  }
  k_dec<<<BB*64, 320, 0, stream>>>(hbuf, dec_w, dec_b, out);
}

// Round 4
// 943.753 us; speedup vs baseline: 4.2060x; 4.2060x over previous
//
#include <hip/hip_runtime.h>
#include <math.h>

#define BB   16
#define TFULL 4096
#define T2   2048
#define LSEQ 2019
#define HSTR 2048
#define CIN  64
#define CO   32
#define HD   64
#define NST  64
#define NLAY 8
#define DOUT 640
#define EPSF 1e-5f
#define NCH  32
#define CHL  64

static __device__ __forceinline__ float sigm(float x){ return 1.f/(1.f + __expf(-x)); }
static __device__ __forceinline__ float gelu_(float x){ return 0.5f*x*(1.f + erff(x*0.7071067811865475f)); }

// ---------------- Stage A: pw1 conv + GN1 partial stats ----------------
__global__ void __launch_bounds__(256) k_pw1(const float* __restrict__ x,
                                             const float* __restrict__ w,
                                             const float* __restrict__ bias,
                                             float* __restrict__ u1,
                                             float* __restrict__ stats){
  int blk = blockIdx.x;
  int b  = blk >> 6;
  int t0 = (blk & 63) << 6;
  __shared__ float xs[CIN][64];
  __shared__ float wsm[CO*CIN];
  __shared__ float red[8];
  int tid = threadIdx.x;
  for (int i = tid; i < CIN*64; i += 256){
    int c = i >> 6, t = i & 63;
    xs[c][t] = x[((long)(b*CIN + c))*TFULL + t0 + t];
  }
  for (int i = tid; i < CO*CIN; i += 256) wsm[i] = w[i];
  __syncthreads();
  int t  = tid & 63;
  int o0 = tid >> 6;
  float lsum = 0.f, lsq = 0.f;
  for (int o = o0; o < CO; o += 4){
    float acc = bias[o];
    #pragma unroll
    for (int c = 0; c < CIN; ++c) acc = fmaf(wsm[o*CIN + c], xs[c][t], acc);
    u1[((long)(b*CO + o))*TFULL + t0 + t] = acc;
    lsum += acc; lsq += acc*acc;
  }
  #pragma unroll
  for (int off = 32; off; off >>= 1){ lsum += __shfl_down(lsum, off); lsq += __shfl_down(lsq, off); }
  if ((tid & 63) == 0){ red[tid>>6] = lsum; red[4 + (tid>>6)] = lsq; }
  __syncthreads();
  if (tid == 0){
    atomicAdd(&stats[b],      red[0]+red[1]+red[2]+red[3]);
    atomicAdd(&stats[16 + b], red[4]+red[5]+red[6]+red[7]);
  }
}

__global__ void k_gnstat(float* __restrict__ stats, int which, float cnt){
  int b = threadIdx.x;
  if (b < BB){
    int o = which * 64;
    float m = stats[o + b] / cnt;
    float v = stats[o + 16 + b] / cnt - m*m;
    stats[o + 32 + b] = m;
    stats[o + 48 + b] = rsqrtf(v + EPSF);
  }
}

// ---------------- Stage A3: GN1 apply + GLU(time) + SiLU ----------------
__global__ void __launch_bounds__(256) k_glu_silu(const float* __restrict__ u1,
                                                  const float* __restrict__ g,
                                                  const float* __restrict__ bb,
                                                  const float* __restrict__ stats,
                                                  float* __restrict__ u2){
  int blk = blockIdx.x;
  int b  = blk >> 5;
  int t0 = (blk & 31) << 6;
  float m = stats[32 + b], r = stats[48 + b];
  int tid = threadIdx.x;
  int t = t0 + (tid & 63);
  for (int c = tid >> 6; c < CO; c += 4){
    long base = ((long)(b*CO + c))*TFULL;
    float a  = u1[base + t];
    float bv = u1[base + t + T2];
    float gc = g[c], bc = bb[c];
    a  = (a  - m)*r*gc + bc;
    bv = (bv - m)*r*gc + bc;
    float z = a * sigm(bv);
    z = z * sigm(z);
    u2[((long)(b*CO + c))*T2 + t] = z;
  }
}

// ---------------- Stage B1: depthwise conv (K=32, pad 1) + GN2 partial stats ----------------
__global__ void __launch_bounds__(256) k_dconv(const float* __restrict__ u2,
                                               const float* __restrict__ w,
                                               const float* __restrict__ bias,
                                               float* __restrict__ v,
                                               float* __restrict__ stats){
  int blk = blockIdx.x;
  int b = blk >> 5, c = blk & 31;
  __shared__ float row[T2 + 2];
  __shared__ float red[8];
  int tid = threadIdx.x;
  if (tid == 0){ row[0] = 0.f; row[T2 + 1] = 0.f; }
  const float* src = u2 + ((long)(b*CO + c))*T2;
  for (int i = tid; i < T2; i += 256) row[1 + i] = src[i];
  __syncthreads();
  float wk[32];
  #pragma unroll
  for (int k = 0; k < 32; ++k) wk[k] = w[c*32 + k];
  float bc = bias[c];
  float lsum = 0.f, lsq = 0.f;
  float* dst = v + ((long)(b*CO + c))*LSEQ;
  for (int t = tid; t < LSEQ; t += 256){
    float acc = bc;
    #pragma unroll
    for (int k = 0; k < 32; ++k) acc = fmaf(wk[k], row[t + k], acc);
    dst[t] = acc;
    lsum += acc; lsq += acc*acc;
  }
  #pragma unroll
  for (int off = 32; off; off >>= 1){ lsum += __shfl_down(lsum, off); lsq += __shfl_down(lsq, off); }
  if ((tid & 63) == 0){ red[tid>>6] = lsum; red[4 + (tid>>6)] = lsq; }
  __syncthreads();
  if (tid == 0){
    atomicAdd(&stats[64 + b], red[0]+red[1]+red[2]+red[3]);
    atomicAdd(&stats[80 + b], red[4]+red[5]+red[6]+red[7]);
  }
}

// ---------------- Stage B3: GN2 apply + pw2 + encoder -> h (B,HD,HSTR) ----------------
__global__ void __launch_bounds__(256) k_pw2enc(const float* __restrict__ v,
                                                const float* __restrict__ g2,
                                                const float* __restrict__ b2,
                                                const float* __restrict__ pw2w,
                                                const float* __restrict__ pw2b,
                                                const float* __restrict__ encw,
                                                const float* __restrict__ encb,
                                                const float* __restrict__ stats,
                                                float* __restrict__ h){
  int blk = blockIdx.x;
  int b  = blk >> 5;
  int t0 = (blk & 31) << 6;
  int tcnt = min(64, LSEQ - t0);
  __shared__ float vn[CO][64];
  __shared__ float p2[CO*CO];
  __shared__ float ew[CO*HD];
  __shared__ float u3[4][CO];
  __shared__ float hout[HD][65];
  int tid = threadIdx.x;
  float m = stats[96 + b], r = stats[112 + b];
  for (int i = tid; i < CO*CO; i += 256){
    int o = i & 31, c = i >> 5;
    p2[c*CO + o] = pw2w[o*CO + c];
  }
  for (int i = tid; i < CO*HD; i += 256) ew[i] = encw[i];
  for (int i = tid; i < CO*64; i += 256){
    int c = i >> 6, t = i & 63;
    float val = 0.f;
    if (t < tcnt) val = v[((long)(b*CO + c))*LSEQ + t0 + t];
    vn[c][t] = (val - m)*r*g2[c] + b2[c];
  }
  __syncthreads();
  int wv = tid >> 6, ln = tid & 63;
  for (int i = 0; i < 16; ++i){
    int tt = wv*16 + i;
    if (ln < CO){
      float acc = pw2b[ln];
      #pragma unroll
      for (int c = 0; c < CO; ++c) acc = fmaf(p2[c*CO + ln], vn[c][tt], acc);
      u3[wv][ln] = acc;
    }
    float hacc = encb[ln];
    #pragma unroll
    for (int c = 0; c < CO; ++c) hacc = fmaf(ew[c*HD + ln], u3[wv][c], hacc);
    hout[ln][tt] = hacc;
  }
  __syncthreads();
  for (int i = tid; i < HD*64; i += 256){
    int d = i >> 6, t = i & 63;
    if (t < tcnt) h[((long)(b*HD + d))*HSTR + t0 + t] = hout[d][t];
  }
}

// ---------------- S4D coefficients for ALL layers ----------------
__global__ void k_coef(const float* __restrict__ log_dt, const float* __restrict__ logA,
                       const float* __restrict__ Aim, const float* __restrict__ Cre,
                       const float* __restrict__ Cim, float* __restrict__ coef){
  int blk = blockIdx.x;
  int l = blk >> 6, hh = blk & 63;
  int n = threadIdx.x;
  float dt = expf(log_dt[l*HD + hh]);
  int idx = (l*HD + hh)*NST + n;
  float Ar = -expf(logA[idx]);
  float Ai = Aim[idx];
  float dr = Ar*dt, di = Ai*dt;
  float er = expf(dr);
  float wr = er*cosf(di), wi = er*sinf(di);
  float inv = 1.f/(Ar*Ar + Ai*Ai);
  float xr = wr - 1.f, xi = wi;
  float qr = (xr*Ar + xi*Ai)*inv;
  float qi = (xi*Ar - xr*Ai)*inv;
  float cr = Cre[idx], ci = Cim[idx];
  float cdr = cr*qr - ci*qi;
  float cdi = cr*qi + ci*qr;
  float* cl = coef + l*4*HD*NST;
  int hn = hh*NST + n;
  cl[hn]            = wr;
  cl[HD*NST + hn]   = wi;
  cl[2*HD*NST + hn] = cdr;
  cl[3*HD*NST + hn] = cdi;
}

// ---------------- S4D chunk-parallel scan ----------------
// E2p[np][k] = float4 (2cd_{2np} w^k .re/.im, 2cd_{2np+1} w^k .re/.im), k=0..64
// Register-light: phase1 uses float2 LDS broadcast reads; phase3 tiles 2 chunks.
__global__ void __launch_bounds__(256) k_s4d(const float* __restrict__ h,
                                             const float* __restrict__ coef,
                                             int layer, float* __restrict__ y){
  int blk = blockIdx.x;
  int b = blk >> 6, hh = blk & 63;
  __shared__ float u_s[2048];
  __shared__ float E2p[32*65*4];
  __shared__ float S_s[NCH*128];
  __shared__ float Kpad[128];
  int tid = threadIdx.x;
  int n = tid & 63, q = tid >> 6;
  const float* cl = coef + layer*4*HD*NST;
  int hn = hh*NST + n;
  float wr  = cl[hn];
  float wi  = cl[HD*NST + hn];
  float cdr = cl[2*HD*NST + hn];
  float cdi = cl[3*HD*NST + hn];
  const float* up = h + ((long)(b*HD + hh))*HSTR;

  {
    int base = tid*8;
    if (base + 8 <= LSEQ){
      *(float4*)&u_s[base]     = *(const float4*)(up + base);
      *(float4*)&u_s[base + 4] = *(const float4*)(up + base + 4);
    } else {
      #pragma unroll
      for (int k = 0; k < 8; ++k){
        int t = base + k;
        u_s[t] = (t < LSEQ) ? up[t] : 0.f;
      }
    }
  }
  if (tid < 64) Kpad[tid] = 0.f;

  // build E2p rows: thread (n,q) fills k in [16q,16q+16) (q==3: +17 incl k=64)
  {
    float ar = wr, ai = wi;
    #pragma unroll
    for (int s = 0; s < 4; ++s){ float t2 = ar*ar - ai*ai; ai = 2.f*ar*ai; ar = t2; }
    float pr = 1.f, pi = 0.f;
    for (int k = 0; k < q; ++k){ float t2 = pr*ar - pi*ai; pi = pr*ai + pi*ar; pr = t2; }
    int np = n >> 1, par = n & 1;
    float* bp = &E2p[(np*65 + q*16)*4 + par*2];
    int cnt = (q == 3) ? 17 : 16;
    for (int k = 0; k < cnt; ++k){
      float2 ev;
      ev.x = 2.f*(cdr*pr - cdi*pi);
      ev.y = 2.f*(cdr*pi + cdi*pr);
      *(float2*)bp = ev;
      float t2 = pr*wr - pi*wi; pi = pr*wi + pi*wr; pr = t2;
      bp += 4;
    }
  }
  __syncthreads();

  // phase 1: per-chunk decayed input sums (wave q owns chunks q*8..q*8+7)
  int cbase = q*8;
  {
    float vr[8], vi[8];
    #pragma unroll
    for (int c8 = 0; c8 < 8; ++c8){ vr[c8] = 0.f; vi[c8] = 0.f; }
    for (int j2 = 0; j2 < 64; j2 += 2){
      #pragma unroll
      for (int c8 = 0; c8 < 8; ++c8){
        float2 uu = *(const float2*)&u_s[(cbase + c8)*64 + j2];
        float nr = fmaf(wr, vr[c8], fmaf(-wi, vi[c8], uu.x));
        float ni = fmaf(wr, vi[c8], wi*vr[c8]);
        float nr2 = fmaf(wr, nr, fmaf(-wi, ni, uu.y));
        float ni2 = fmaf(wr, ni, wi*nr);
        vr[c8] = nr2; vi[c8] = ni2;
      }
    }
    #pragma unroll
    for (int c8 = 0; c8 < 8; ++c8){
      S_s[(cbase + c8)*128 + 2*n]     = vr[c8];
      S_s[(cbase + c8)*128 + 2*n + 1] = vi[c8];
    }
  }
  __syncthreads();

  // phase 2 (wave 0): K taps + chunk-state scan
  if (q == 0){
    float ks = 0.f;
    for (int np = 0; np < 32; ++np){
      float4 e = *(const float4*)&E2p[(np*65 + n)*4];
      ks += e.x + e.z;
    }
    Kpad[64 + n] = ks;
    float ar = wr, ai = wi;
    #pragma unroll
    for (int s = 0; s < 6; ++s){ float t2 = ar*ar - ai*ai; ai = 2.f*ar*ai; ar = t2; }
    float sr = 0.f, si = 0.f;
    for (int c = 0; c < NCH; ++c){
      float vr2 = S_s[c*128 + 2*n], vi2 = S_s[c*128 + 2*n + 1];
      S_s[c*128 + 2*n]     = sr;
      S_s[c*128 + 2*n + 1] = si;
      float nr = fmaf(ar, sr, fmaf(-ai, si, vr2));
      float ni = fmaf(ar, si, fmaf(ai, sr, vi2));
      sr = nr; si = ni;
    }
  }
  __syncthreads();

  // phase 3: 4 groups of 2 chunks, lane = i
  float* yo = y + ((long)(b*HD + hh))*HSTR;
  int i = n;
  for (int g = 0; g < 4; ++g){
    int c0 = cbase + g*2;
    float acc0 = 0.f, acc1 = 0.f;
    {
      const float* S0 = &S_s[(c0+0)*128];
      const float* S1 = &S_s[(c0+1)*128];
      for (int np = 0; np < 32; ++np){
        float4 e  = *(const float4*)&E2p[(np*65 + i + 1)*4];
        float4 s0 = *(const float4*)&S0[np*4];
        float4 s1 = *(const float4*)&S1[np*4];
        acc0 = fmaf(e.x,s0.x, fmaf(-e.y,s0.y, fmaf(e.z,s0.z, fmaf(-e.w,s0.w, acc0))));
        acc1 = fmaf(e.x,s1.x, fmaf(-e.y,s1.y, fmaf(e.z,s1.z, fmaf(-e.w,s1.w, acc1))));
      }
    }
    {
      const float* U0 = &u_s[(c0+0)*64];
      const float* U1 = &u_s[(c0+1)*64];
      for (int j2 = 0; j2 < 64; j2 += 2){
        float2 u0 = *(const float2*)&U0[j2];
        float2 u1v= *(const float2*)&U1[j2];
        float k0 = Kpad[64 + i - j2];
        float k1 = Kpad[63 + i - j2];
        acc0 = fmaf(k0, u0.x, fmaf(k1, u0.y, acc0));
        acc1 = fmaf(k0, u1v.x, fmaf(k1, u1v.y, acc1));
      }
    }
    int t0c = c0*64 + i;
    if (t0c      < LSEQ) yo[t0c]      = acc0;
    if (t0c + 64 < LSEQ) yo[t0c + 64] = acc1;
  }
}

// ---------------- S4D post: register-tiled GEMM + GLU + residual + LN ----------------
__global__ void __launch_bounds__(256) k_post(const float* __restrict__ y,
                                              float* __restrict__ h,
                                              const float* __restrict__ D,
                                              const float* __restrict__ ow,
                                              const float* __restrict__ ob,
                                              const float* __restrict__ lng,
                                              const float* __restrict__ lnb,
                                              int layer){
  int blk = blockIdx.x;
  int b  = blk >> 5;
  int t0 = (blk & 31) << 6;
  __shared__ float Ws[64*128];     // [c][o]
  __shared__ float Ys[64*68];      // [c][t]; reused as z-buffer
  __shared__ float mstat[64], rstat[64];
  int tid = threadIdx.x;
  const float* owp = ow + layer*2*HD*HD;
  const float* obp = ob + layer*2*HD;
  {
    int o = tid >> 1, cs = (tid & 1)*32;
    const float* wrow = owp + o*HD + cs;
    #pragma unroll
    for (int k = 0; k < 8; ++k){
      float4 w4 = *(const float4*)(wrow + k*4);
      Ws[(cs + k*4 + 0)*128 + o] = w4.x;
      Ws[(cs + k*4 + 1)*128 + o] = w4.y;
      Ws[(cs + k*4 + 2)*128 + o] = w4.z;
      Ws[(cs + k*4 + 3)*128 + o] = w4.w;
    }
  }
  {
    int c = tid >> 2, qq = tid & 3;
    float dl = D[layer*HD + c];
    const float* yrow = y + ((long)(b*HD + c))*HSTR + t0 + qq*16;
    const float* hrow = h + ((long)(b*HD + c))*HSTR + t0 + qq*16;
    #pragma unroll
    for (int k = 0; k < 4; ++k){
      float4 yv = *(const float4*)(yrow + k*4);
      float4 hv = *(const float4*)(hrow + k*4);
      float4 g4;
      g4.x = gelu_(fmaf(hv.x, dl, yv.x));
      g4.y = gelu_(fmaf(hv.y, dl, yv.y));
      g4.z = gelu_(fmaf(hv.z, dl, yv.z));
      g4.w = gelu_(fmaf(hv.w, dl, yv.w));
      *(float4*)&Ys[c*68 + qq*16 + k*4] = g4;
    }
  }
  __syncthreads();
  int og = tid >> 4, tg = tid & 15;
  int o0 = og*4, tt0 = tg*4;
  float accA[4][4], accG[4][4];
  #pragma unroll
  for (int i = 0; i < 4; ++i){
    float ba = obp[o0 + i], bg = obp[64 + o0 + i];
    #pragma unroll
    for (int j = 0; j < 4; ++j){ accA[i][j] = ba; accG[i][j] = bg; }
  }
  for (int c = 0; c < 64; ++c){
    float4 wa = *(const float4*)&Ws[c*128 + o0];
    float4 wg = *(const float4*)&Ws[c*128 + 64 + o0];
    float4 yv = *(const float4*)&Ys[c*68 + tt0];
    float yvv[4] = {yv.x, yv.y, yv.z, yv.w};
    float wav[4] = {wa.x, wa.y, wa.z, wa.w};
    float wgv[4] = {wg.x, wg.y, wg.z, wg.w};
    #pragma unroll
    for (int i = 0; i < 4; ++i){
      #pragma unroll
      for (int j = 0; j < 4; ++j){
        accA[i][j] = fmaf(wav[i], yvv[j], accA[i][j]);
        accG[i][j] = fmaf(wgv[i], yvv[j], accG[i][j]);
      }
    }
  }
  __syncthreads();
  float r[4][4];
  #pragma unroll
  for (int i = 0; i < 4; ++i){
    int c = o0 + i;
    const float* hrow = h + ((long)(b*HD + c))*HSTR + t0 + tt0;
    #pragma unroll
    for (int j = 0; j < 4; ++j){
      int t = t0 + tt0 + j;
      float hold = (t < LSEQ) ? hrow[j] : 0.f;
      float z = accA[i][j] * sigm(accG[i][j]);
      r[i][j] = z + hold;
    }
    float4 rr = {r[i][0], r[i][1], r[i][2], r[i][3]};
    *(float4*)&Ys[c*68 + tt0] = rr;
  }
  __syncthreads();
  if (tid < 64){
    float s1 = 0.f, s2 = 0.f;
    for (int c = 0; c < 64; ++c){
      float v = Ys[c*68 + tid];
      s1 += v; s2 += v*v;
    }
    float m = s1 * (1.f/64.f);
    float var = fmaf(-m, m, s2 * (1.f/64.f));
    mstat[tid] = m;
    rstat[tid] = rsqrtf(var + EPSF);
  }
  __syncthreads();
  #pragma unroll
  for (int i = 0; i < 4; ++i){
    int c = o0 + i;
    float gl = lng[layer*HD + c], bl = lnb[layer*HD + c];
    float* hrow = h + ((long)(b*HD + c))*HSTR + t0 + tt0;
    if (t0 + tt0 + 3 < LSEQ){
      float4 o4v;
      o4v.x = fmaf((r[i][0] - mstat[tt0+0])*rstat[tt0+0], gl, bl);
      o4v.y = fmaf((r[i][1] - mstat[tt0+1])*rstat[tt0+1], gl, bl);
      o4v.z = fmaf((r[i][2] - mstat[tt0+2])*rstat[tt0+2], gl, bl);
      o4v.w = fmaf((r[i][3] - mstat[tt0+3])*rstat[tt0+3], gl, bl);
      *(float4*)hrow = o4v;
    } else {
      #pragma unroll
      for (int j = 0; j < 4; ++j){
        int t = t0 + tt0 + j;
        if (t < LSEQ) hrow[j] = fmaf((r[i][j] - mstat[tt0+j])*rstat[tt0+j], gl, bl);
      }
    }
  }
}

// ---------------- Decoder: register-blocked, weight-reuse GEMM ----------------
__global__ void __launch_bounds__(320) k_dec(const float* __restrict__ h,
                                             const float* __restrict__ w,
                                             const float* __restrict__ bias,
                                             float* __restrict__ out){
  int blk = blockIdx.x;
  int b  = blk >> 6;
  int t0 = (blk & 63) << 5;
  __shared__ float hl[HD][32];
  int tid = threadIdx.x;
  for (int i = tid; i < HD*32; i += 320){
    int d = i >> 5, t = i & 31;
    int tt = t0 + t;
    hl[d][t] = (tt < LSEQ) ? h[((long)(b*HD + d))*HSTR + tt] : 0.f;
  }
  __syncthreads();
  int o4 = tid % 160, th = tid / 160;
  int tb = th * 16;
  float4 acc[16];
  const float4 b4 = *(const float4*)(bias + o4*4);
  #pragma unroll
  for (int i = 0; i < 16; ++i) acc[i] = b4;
  const float* wp = w + o4*4;
  for (int d = 0; d < HD; ++d){
    float4 w4 = *(const float4*)(wp + (long)d*DOUT);
    #pragma unroll
    for (int ii = 0; ii < 4; ++ii){
      float4 h4 = *(const float4*)&hl[d][tb + ii*4];
      float hvv[4] = {h4.x, h4.y, h4.z, h4.w};
      #pragma unroll
      for (int jj = 0; jj < 4; ++jj){
        int i = ii*4 + jj;
        acc[i].x = fmaf(hvv[jj], w4.x, acc[i].x);
        acc[i].y = fmaf(hvv[jj], w4.y, acc[i].y);
        acc[i].z = fmaf(hvv[jj], w4.z, acc[i].z);
        acc[i].w = fmaf(hvv[jj], w4.w, acc[i].w);
      }
    }
  }
  #pragma unroll
  for (int i = 0; i < 16; ++i){
    int t = t0 + tb + i;
    if (t < LSEQ) *(float4*)(out + ((long)(b*LSEQ) + t)*DOUT + o4*4) = acc[i];
  }
}

extern "C" void kernel_launch(void* const* d_in, const int* in_sizes, int n_in,
                              void* d_out, int out_size, void* d_ws, size_t ws_size,
                              hipStream_t stream){
  const float* x     = (const float*)d_in[0];
  const float* pw1_w = (const float*)d_in[1];
  const float* pw1_b = (const float*)d_in[2];
  const float* gn1_g = (const float*)d_in[3];
  const float* gn1_b = (const float*)d_in[4];
  const float* dw_w  = (const float*)d_in[5];
  const float* dw_b  = (const float*)d_in[6];
  const float* gn2_g = (const float*)d_in[7];
  const float* gn2_b = (const float*)d_in[8];
  const float* pw2_w = (const float*)d_in[9];
  const float* pw2_b = (const float*)d_in[10];
  const float* enc_w = (const float*)d_in[11];
  const float* enc_b = (const float*)d_in[12];
  const float* log_dt= (const float*)d_in[13];
  const float* logA  = (const float*)d_in[14];
  const float* Aim   = (const float*)d_in[15];
  const float* Cre   = (const float*)d_in[16];
  const float* Cim   = (const float*)d_in[17];
  const float* Dp    = (const float*)d_in[18];
  const float* owp   = (const float*)d_in[19];
  const float* obp   = (const float*)d_in[20];
  const float* lng   = (const float*)d_in[21];
  const float* lnb   = (const float*)d_in[22];
  const float* dec_w = (const float*)d_in[23];
  const float* dec_b = (const float*)d_in[24];
  float* out = (float*)d_out;

  float* ws   = (float*)d_ws;
  float* u1   = ws;
  float* u2   = u1 + 2097152;
  float* vv   = u2 + 1048576;
  float* hbuf = vv + 1033728;
  float* coef = hbuf + 2097152;
  float* stats= coef + 131072;
  float* ybuf = u1;

  hipMemsetAsync(stats, 0, 128*sizeof(float), stream);
  k_coef<<<NLAY*HD, 64, 0, stream>>>(log_dt, logA, Aim, Cre, Cim, coef);
  k_pw1<<<BB*64, 256, 0, stream>>>(x, pw1_w, pw1_b, u1, stats);
  k_gnstat<<<1, 64, 0, stream>>>(stats, 0, (float)(CO*TFULL));
  k_glu_silu<<<BB*32, 256, 0, stream>>>(u1, gn1_g, gn1_b, stats, u2);
  k_dconv<<<BB*CO, 256, 0, stream>>>(u2, dw_w, dw_b, vv, stats);
  k_gnstat<<<1, 64, 0, stream>>>(stats, 1, (float)(CO*LSEQ));
  k_pw2enc<<<BB*32, 256, 0, stream>>>(vv, gn2_g, gn2_b, pw2_w, pw2_b, enc_w, enc_b, stats, hbuf);
  for (int l = 0; l < NLAY; ++l){
    k_s4d<<<BB*HD, 256, 0, stream>>>(hbuf, coef, l, ybuf);
    k_post<<<BB*32, 256, 0, stream>>>(ybuf, hbuf, Dp, owp, obp, lng, lnb, l);
  }
  k_dec<<<BB*64, 320, 0, stream>>>(hbuf, dec_w, dec_b, out);
}